// Round 1
// baseline (612.814 us; speedup 1.0000x reference)
//
#include <hip/hip_runtime.h>
#include <math.h>

#define BATCH 4
#define NPTS  8192
#define KNN   16
#define KK    17              // top-17 incl. self (self contributes 0 to loss)
#define QPB   64              // queries per block
#define SPLITS 4              // candidate-range splits (threads per query)
#define BLOCK (QPB*SPLITS)    // 256
#define RANGE (NPTS/SPLITS)   // 2048
#define TOTAL_EDGES (BATCH*NPTS*KNN)  // 524288

__global__ void pel_zero_ws(float* ws) { ws[0] = 0.0f; }

__global__ void pel_finalize(const float* __restrict__ ws, float* __restrict__ out) {
    out[0] = ws[0] * (1.0f / (float)TOTAL_EDGES);
}

__global__ __launch_bounds__(BLOCK)
void pel_knn_loss(const float* __restrict__ pref,
                  const float* __restrict__ pts,
                  float* __restrict__ ws)
{
    __shared__ float s_vals[BLOCK][KK + 1];   // +1 pad vs bank conflicts (~18 KB)
    __shared__ float s_tau[QPB];
    __shared__ float s_part[BLOCK / 64];

    const int t  = threadIdx.x;
    const int lq = t & (QPB - 1);     // query within block
    const int sp = t >> 6;            // split 0..3
    const int qg = blockIdx.x * QPB + lq;
    const int b  = qg >> 13;          // / 8192
    const int i  = qg & (NPTS - 1);

    const float* __restrict__ Pr = pref + (size_t)b * (NPTS * 3);
    const float* __restrict__ Pp = pts  + (size_t)b * (NPTS * 3);

    const float xi = Pr[3 * i + 0];
    const float yi = Pr[3 * i + 1];
    const float zi = Pr[3 * i + 2];

    // ---------------- pass 1: top-17 d2 values over this split's range ----
    float a[KK];
    #pragma unroll
    for (int k = 0; k < KK; ++k) a[k] = 3.0e38f;

    const int j0 = sp * RANGE;
    for (int j = j0; j < j0 + RANGE; j += 4) {
        const float4 v0 = *(const float4*)(Pr + 3 * j);
        const float4 v1 = *(const float4*)(Pr + 3 * j + 4);
        const float4 v2 = *(const float4*)(Pr + 3 * j + 8);
        const float cx[4] = { v0.x, v0.w, v1.z, v2.y };
        const float cy[4] = { v0.y, v1.x, v1.w, v2.z };
        const float cz[4] = { v0.z, v1.y, v2.x, v2.w };
        #pragma unroll
        for (int u = 0; u < 4; ++u) {
            const float dx = cx[u] - xi;
            const float dy = cy[u] - yi;
            const float dz = cz[u] - zi;
            const float d2 = fmaf(dx, dx, fmaf(dy, dy, dz * dz));
            if (d2 < a[KK - 1]) {
                // sorted-ascending insert, values only: 2 ops/slot
                #pragma unroll
                for (int k = KK - 1; k >= 1; --k)
                    a[k] = fminf(a[k], fmaxf(a[k - 1], d2));
                a[0] = fminf(a[0], d2);
            }
        }
    }

    #pragma unroll
    for (int k = 0; k < KK; ++k) s_vals[t][k] = a[k];
    __syncthreads();

    // ---------------- merge 4 sorted runs -> tau (first wave only) --------
    if (t < QPB) {
        float m[KK];
        #pragma unroll
        for (int k = 0; k < KK; ++k) m[k] = s_vals[t][k];
        for (int s = 1; s < SPLITS; ++s) {
            const float* run = s_vals[t + s * QPB];
            for (int k = 0; k < KK; ++k) {
                const float c = run[k];
                if (c >= m[KK - 1]) break;     // runs sorted ascending
                #pragma unroll
                for (int kk = KK - 1; kk >= 1; --kk)
                    m[kk] = fminf(m[kk], fmaxf(m[kk - 1], c));
                m[0] = fminf(m[0], c);
            }
        }
        s_tau[t] = m[KK - 1];
    }
    __syncthreads();
    const float tau = s_tau[lq];

    // ---------------- pass 2: rescan, accept d2 <= tau, accumulate loss ---
    const float pxi = Pp[3 * i + 0];
    const float pyi = Pp[3 * i + 1];
    const float pzi = Pp[3 * i + 2];

    float acc = 0.0f;
    for (int j = j0; j < j0 + RANGE; j += 4) {
        const float4 v0 = *(const float4*)(Pr + 3 * j);
        const float4 v1 = *(const float4*)(Pr + 3 * j + 4);
        const float4 v2 = *(const float4*)(Pr + 3 * j + 8);
        const float cx[4] = { v0.x, v0.w, v1.z, v2.y };
        const float cy[4] = { v0.y, v1.x, v1.w, v2.z };
        const float cz[4] = { v0.z, v1.y, v2.x, v2.w };
        #pragma unroll
        for (int u = 0; u < 4; ++u) {
            const float dx = cx[u] - xi;
            const float dy = cy[u] - yi;
            const float dz = cz[u] - zi;
            const float d2r = fmaf(dx, dx, fmaf(dy, dy, dz * dz));
            if (d2r <= tau) {
                const float* q = Pp + 3 * (j + u);
                const float ex = q[0] - pxi;
                const float ey = q[1] - pyi;
                const float ez = q[2] - pzi;
                const float d2p = fmaf(ex, ex, fmaf(ey, ey, ez * ez));
                acc += fabsf(sqrtf(d2r) - sqrtf(d2p));
            }
        }
    }

    // ---------------- block reduction + one atomic ------------------------
    #pragma unroll
    for (int off = 32; off > 0; off >>= 1)
        acc += __shfl_down(acc, off, 64);

    const int wid = t >> 6, lid = t & 63;
    if (lid == 0) s_part[wid] = acc;
    __syncthreads();
    if (t == 0) {
        float s = 0.0f;
        #pragma unroll
        for (int w = 0; w < BLOCK / 64; ++w) s += s_part[w];
        atomicAdd(ws, s);
    }
}

extern "C" void kernel_launch(void* const* d_in, const int* in_sizes, int n_in,
                              void* d_out, int out_size, void* d_ws, size_t ws_size,
                              hipStream_t stream) {
    const float* pref = (const float*)d_in[0];
    const float* pts  = (const float*)d_in[1];
    float* ws  = (float*)d_ws;
    float* out = (float*)d_out;

    pel_zero_ws<<<1, 1, 0, stream>>>(ws);
    const int nq = BATCH * NPTS;                 // 32768 queries
    pel_knn_loss<<<nq / QPB, BLOCK, 0, stream>>>(pref, pts, ws);
    pel_finalize<<<1, 1, 0, stream>>>(ws, out);
}

// Round 2
// 393.009 us; speedup vs baseline: 1.5593x; 1.5593x over previous
//
#include <hip/hip_runtime.h>
#include <math.h>

#define BATCH 4
#define NPTS  8192
#define KNN   16
#define KK    17              // top-17 incl. self (self contributes 0 to loss)
#define QPB   32              // queries per block
#define SPLITS 8              // threads per query
#define BLOCK 256
#define RANGE (NPTS/SPLITS)   // 1024
#define SAMPLE 128            // phase-A sample per thread (union = 1024 = N/8)
#define AL    8               // phase-A per-thread list size
#define CAP   32              // phase-B buffer capacity per thread
#define TOTAL_EDGES (BATCH*NPTS*KNN)  // 524288

// pack (x,y,z,||x||^2) for ref points; also zero the loss accumulator
__global__ void pel_pack(const float* __restrict__ pref, float4* __restrict__ p4,
                         float* __restrict__ acc) {
    if (blockIdx.x == 0 && threadIdx.x == 0) acc[0] = 0.0f;
    const int idx = blockIdx.x * blockDim.x + threadIdx.x;
    if (idx < BATCH * NPTS) {
        const float x = pref[3*idx], y = pref[3*idx+1], z = pref[3*idx+2];
        p4[idx] = make_float4(x, y, z, fmaf(x, x, fmaf(y, y, z*z)));
    }
}

__global__ void pel_zero(float* acc) { acc[0] = 0.0f; }

__global__ void pel_finalize(const float* __restrict__ acc, float* __restrict__ out) {
    out[0] = acc[0] * (1.0f / (float)TOTAL_EDGES);
}

// e(j) = ||xj||^2 - 2*xi.xj  (monotone in d2 = e + ||xi||^2)
template <bool PACKED>
__device__ __forceinline__ float cand_e(const float4* __restrict__ Pq,
                                        const float* __restrict__ Pr,
                                        int j, float xi, float yi, float zi) {
    if (PACKED) {
        const float4 p = Pq[j];
        const float dot = fmaf(p.x, xi, fmaf(p.y, yi, p.z * zi));
        return fmaf(-2.0f, dot, p.w);
    } else {
        const float x = Pr[3*j], y = Pr[3*j+1], z = Pr[3*j+2];
        const float sq = fmaf(x, x, fmaf(y, y, z*z));
        const float dot = fmaf(x, xi, fmaf(y, yi, z * zi));
        return fmaf(-2.0f, dot, sq);
    }
}

template <bool PACKED>
__global__ __launch_bounds__(BLOCK)
void pel_main(const float4* __restrict__ P4, const float* __restrict__ pref,
              const float* __restrict__ pts, float* __restrict__ acc_ws)
{
    __shared__ float s_c17[KK][BLOCK];            // k-major: conflict-free merges
    __shared__ unsigned short s_bufJ[CAP][BLOCK]; // survivor indices
    __shared__ float s_tau[QPB];
    __shared__ float s_part[BLOCK / 64];

    const int t  = threadIdx.x;
    const int lq = t & (QPB - 1);
    const int sp = t >> 5;
    const int q  = blockIdx.x * QPB + lq;
    const int b  = q >> 13;
    const int i  = q & (NPTS - 1);

    const float4* __restrict__ Pq = P4 + b * NPTS;
    const float*  __restrict__ Pr = pref + (size_t)b * NPTS * 3;
    const float*  __restrict__ Pp = pts  + (size_t)b * NPTS * 3;

    const float xi = Pr[3*i], yi = Pr[3*i+1], zi = Pr[3*i+2];
    const float sqi = fmaf(xi, xi, fmaf(yi, yi, zi*zi));
    const int base = sp * RANGE;

    // ---- Phase A: top-AL of a SAMPLE-candidate prefix (cheap 16-op insert) ----
    float al[AL];
    #pragma unroll
    for (int k = 0; k < AL; ++k) al[k] = 3.0e38f;
    for (int it = 0; it < SAMPLE; ++it) {
        const float e = cand_e<PACKED>(Pq, Pr, base + it, xi, yi, zi);
        if (e < al[AL-1]) {
            #pragma unroll
            for (int k = AL-1; k >= 1; --k) al[k] = fminf(al[k], fmaxf(al[k-1], e));
            al[0] = fminf(al[0], e);
        }
    }
    #pragma unroll
    for (int k = 0; k < AL; ++k) s_c17[k][t] = al[k];
    __syncthreads();
    if (t < QPB) {   // merge 8 sorted runs of AL -> tau0 = 17th of union sample
        float m[KK];
        #pragma unroll
        for (int k = 0; k < KK; ++k) m[k] = 3.0e38f;
        for (int s = 0; s < SPLITS; ++s) {
            const int r = t + s * QPB;
            for (int k = 0; k < AL; ++k) {
                const float c = s_c17[k][r];
                if (c >= m[KK-1]) break;
                #pragma unroll
                for (int kk = KK-1; kk >= 1; --kk) m[kk] = fminf(m[kk], fmaxf(m[kk-1], c));
                m[0] = fminf(m[0], c);
            }
        }
        s_tau[t] = m[KK-1];
    }
    __syncthreads();
    float tauL = s_tau[lq];   // upper bound on true 17th; tightens per-thread

    // ---- Phase B: filter scan, push survivor indices (no sorting) ----
    int cnt = 0;
    for (int j = base; j < base + RANGE; ++j) {
        const float e = cand_e<PACKED>(Pq, Pr, j, xi, yi, zi);
        if (e <= tauL) {
            s_bufJ[cnt][t] = (unsigned short)j;
            ++cnt;
            if (cnt == CAP) {   // rare: keep thread-local top-KK, tighten tauL
                float c17[KK];
                #pragma unroll
                for (int k = 0; k < KK; ++k) c17[k] = 3.0e38f;
                for (int n = 0; n < CAP; ++n) {
                    const float ee = cand_e<PACKED>(Pq, Pr, s_bufJ[n][t], xi, yi, zi);
                    if (ee < c17[KK-1]) {
                        #pragma unroll
                        for (int k = KK-1; k >= 1; --k) c17[k] = fminf(c17[k], fmaxf(c17[k-1], ee));
                        c17[0] = fminf(c17[0], ee);
                    }
                }
                const float th = c17[KK-1];
                int kept = 0;
                for (int n = 0; n < CAP; ++n) {
                    const unsigned short jj = s_bufJ[n][t];
                    const float ee = cand_e<PACKED>(Pq, Pr, jj, xi, yi, zi);
                    if (ee <= th) { s_bufJ[kept][t] = jj; ++kept; }
                }
                cnt = kept;
                tauL = fminf(tauL, th);
            }
        }
    }

    // ---- Phase C: exact per-thread top-KK of survivors, merge -> exact tau ----
    {
        float c17[KK];
        #pragma unroll
        for (int k = 0; k < KK; ++k) c17[k] = 3.0e38f;
        for (int n = 0; n < cnt; ++n) {
            const float ee = cand_e<PACKED>(Pq, Pr, s_bufJ[n][t], xi, yi, zi);
            if (ee < c17[KK-1]) {
                #pragma unroll
                for (int k = KK-1; k >= 1; --k) c17[k] = fminf(c17[k], fmaxf(c17[k-1], ee));
                c17[0] = fminf(c17[0], ee);
            }
        }
        #pragma unroll
        for (int k = 0; k < KK; ++k) s_c17[k][t] = c17[k];
    }
    __syncthreads();
    if (t < QPB) {
        float m[KK];
        #pragma unroll
        for (int k = 0; k < KK; ++k) m[k] = 3.0e38f;
        for (int s = 0; s < SPLITS; ++s) {
            const int r = t + s * QPB;
            for (int k = 0; k < KK; ++k) {
                const float c = s_c17[k][r];
                if (c >= m[KK-1]) break;
                #pragma unroll
                for (int kk = KK-1; kk >= 1; --kk) m[kk] = fminf(m[kk], fmaxf(m[kk-1], c));
                m[0] = fminf(m[0], c);
            }
        }
        s_tau[t] = m[KK-1];   // exact 17th (incl self) of all 8192
    }
    __syncthreads();
    const float tau = s_tau[lq];

    // ---- Phase D: accumulate |dist_ref - dist_pred| over accepted survivors ----
    const float pxi = Pp[3*i], pyi = Pp[3*i+1], pzi = Pp[3*i+2];
    float acc = 0.0f;
    for (int n = 0; n < cnt; ++n) {
        const int jj = s_bufJ[n][t];
        const float ee = cand_e<PACKED>(Pq, Pr, jj, xi, yi, zi);
        if (ee <= tau) {
            const float d2r = fmaxf(ee + sqi, 0.0f);        // guard self/cancellation
            const float ex = Pp[3*jj]   - pxi;
            const float ey = Pp[3*jj+1] - pyi;
            const float ez = Pp[3*jj+2] - pzi;
            const float d2p = fmaf(ex, ex, fmaf(ey, ey, ez*ez));
            acc += fabsf(sqrtf(d2r) - sqrtf(d2p));
        }
    }

    #pragma unroll
    for (int off = 32; off > 0; off >>= 1) acc += __shfl_down(acc, off, 64);
    if ((t & 63) == 0) s_part[t >> 6] = acc;
    __syncthreads();
    if (t == 0) {
        float s = 0.0f;
        #pragma unroll
        for (int w = 0; w < BLOCK / 64; ++w) s += s_part[w];
        atomicAdd(acc_ws, s);
    }
}

extern "C" void kernel_launch(void* const* d_in, const int* in_sizes, int n_in,
                              void* d_out, int out_size, void* d_ws, size_t ws_size,
                              hipStream_t stream) {
    const float* pref = (const float*)d_in[0];
    const float* pts  = (const float*)d_in[1];
    float*  wsf = (float*)d_ws;
    float*  acc = wsf;                       // ws[0]: loss accumulator
    float4* P4  = (float4*)(wsf + 4);        // ws+16B: packed (x,y,z,sq), 512KB
    float*  out = (float*)d_out;

    const size_t need = 16 + (size_t)BATCH * NPTS * sizeof(float4);
    const int nblk = (BATCH * NPTS) / QPB;   // 1024 blocks

    if (ws_size >= need) {
        pel_pack<<<(BATCH*NPTS + 255)/256, 256, 0, stream>>>(pref, P4, acc);
        pel_main<true><<<nblk, BLOCK, 0, stream>>>(P4, pref, pts, acc);
    } else {                                  // fallback: no packed array
        pel_zero<<<1, 1, 0, stream>>>(acc);
        pel_main<false><<<nblk, BLOCK, 0, stream>>>(nullptr, pref, pts, acc);
    }
    pel_finalize<<<1, 1, 0, stream>>>(acc, out);
}

// Round 3
// 302.842 us; speedup vs baseline: 2.0235x; 1.2977x over previous
//
#include <hip/hip_runtime.h>
#include <math.h>

#define BATCH 4
#define NPTS  8192
#define KNN   16
#define KK    17              // top-17 incl. self (self contributes 0 to loss)
#define QPB   32              // queries per block
#define SPLITS 8              // threads per query
#define BLOCK 256
#define RANGE (NPTS/SPLITS)   // 1024
#define SAMPLE 128            // phase-A sample per thread (union = 1024)
#define AL    8               // phase-A per-thread list size
#define CAP   32              // phase-B buffer capacity per thread
#define CHUNK 8               // loads in flight per thread
#define TOTAL_EDGES (BATCH*NPTS*KNN)  // 524288

// pack (x,y,z,||x||^2) for ref AND pred points; zero the loss accumulator
__global__ void pel_pack(const float* __restrict__ pref, const float* __restrict__ pts,
                         float4* __restrict__ p4r, float4* __restrict__ p4p,
                         float* __restrict__ acc) {
    if (blockIdx.x == 0 && threadIdx.x == 0) acc[0] = 0.0f;
    const int idx = blockIdx.x * blockDim.x + threadIdx.x;
    const int n = BATCH * NPTS;
    if (idx < n) {
        float x = pref[3*idx], y = pref[3*idx+1], z = pref[3*idx+2];
        p4r[idx] = make_float4(x, y, z, fmaf(x, x, fmaf(y, y, z*z)));
        x = pts[3*idx]; y = pts[3*idx+1]; z = pts[3*idx+2];
        p4p[idx] = make_float4(x, y, z, fmaf(x, x, fmaf(y, y, z*z)));
    }
}

__global__ void pel_finalize(const float* __restrict__ acc, float* __restrict__ out) {
    out[0] = acc[0] * (1.0f / (float)TOTAL_EDGES);
}

__device__ __forceinline__ float cand_e4(const float4 p, float xi, float yi, float zi) {
    // e(j) = ||xj||^2 - 2*xi.xj   (monotone in d2 = e + ||xi||^2)
    return fmaf(-2.0f, fmaf(p.x, xi, fmaf(p.y, yi, p.z * zi)), p.w);
}

__global__ __launch_bounds__(BLOCK, 4)
void pel_main(const float4* __restrict__ P4r, const float4* __restrict__ P4p,
              float* __restrict__ acc_ws)
{
    __shared__ float s_c17[KK][BLOCK];            // k-major: conflict-free merges
    __shared__ unsigned short s_bufJ[CAP][BLOCK]; // survivor indices
    __shared__ float s_tau[QPB];
    __shared__ float s_part[BLOCK / 64];

    const int t  = threadIdx.x;
    const int lq = t & (QPB - 1);
    const int sp = t >> 5;
    const int q  = blockIdx.x * QPB + lq;
    const int b  = q >> 13;
    const int i  = q & (NPTS - 1);

    const float4* __restrict__ Pq = P4r + b * NPTS;
    const float4* __restrict__ Pp = P4p + b * NPTS;

    const float4 self = Pq[i];
    const float xi = self.x, yi = self.y, zi = self.z, sqi = self.w;
    const int base = sp * RANGE;
    const float4* __restrict__ Pb = Pq + base;

    // ---- Phase A: top-AL over SAMPLE prefix, chunked loads (8 in flight) ----
    float al[AL];
    #pragma unroll
    for (int k = 0; k < AL; ++k) al[k] = 3.0e38f;
    for (int j0 = 0; j0 < SAMPLE; j0 += CHUNK) {
        float4 c[CHUNK];
        #pragma unroll
        for (int u = 0; u < CHUNK; ++u) c[u] = Pb[j0 + u];
        #pragma unroll
        for (int u = 0; u < CHUNK; ++u) {
            const float e = cand_e4(c[u], xi, yi, zi);
            if (e < al[AL-1]) {
                #pragma unroll
                for (int k = AL-1; k >= 1; --k) al[k] = fminf(al[k], fmaxf(al[k-1], e));
                al[0] = fminf(al[0], e);
            }
        }
    }
    #pragma unroll
    for (int k = 0; k < AL; ++k) s_c17[k][t] = al[k];
    __syncthreads();

    // ---- merge 8 sorted AL-runs -> tau0: two half-merges + bitonic 17th ----
    if (t < 64) {
        const int mq = t & 31, half = t >> 5;
        float m[KK];
        #pragma unroll
        for (int k = 0; k < KK; ++k) m[k] = 3.0e38f;
        for (int s = 0; s < SPLITS/2; ++s) {
            const int r = mq + (half * (SPLITS/2) + s) * QPB;
            for (int k = 0; k < AL; ++k) {
                const float c = s_c17[k][r];
                if (c >= m[KK-1]) break;
                #pragma unroll
                for (int kk = KK-1; kk >= 1; --kk) m[kk] = fminf(m[kk], fmaxf(m[kk-1], c));
                m[0] = fminf(m[0], c);
            }
        }
        float tau = -3.0e38f;
        #pragma unroll
        for (int k = 0; k < KK; ++k) {
            const float bk = __shfl(m[KK-1-k], mq + 32, 64);
            tau = fmaxf(tau, fminf(m[k], bk));
        }
        if (half == 0) s_tau[mq] = tau;
    }
    __syncthreads();
    float tauL = s_tau[lq];   // upper bound on true 17th; tightens per-thread

    // ---- Phase B: filter scan, chunked loads, push survivor indices ----
    int cnt = 0;
    for (int j0 = 0; j0 < RANGE; j0 += CHUNK) {
        float4 c[CHUNK];
        #pragma unroll
        for (int u = 0; u < CHUNK; ++u) c[u] = Pb[j0 + u];
        #pragma unroll
        for (int u = 0; u < CHUNK; ++u) {
            const float e = cand_e4(c[u], xi, yi, zi);
            if (e <= tauL) {
                s_bufJ[cnt][t] = (unsigned short)(base + j0 + u);
                if (++cnt == CAP) {
                    // rare self-healing compaction: exact top-KK of buffer
                    float c17[KK];
                    #pragma unroll
                    for (int k = 0; k < KK; ++k) c17[k] = 3.0e38f;
                    for (int n = 0; n < CAP; ++n) {
                        const float ee = cand_e4(Pq[s_bufJ[n][t]], xi, yi, zi);
                        if (ee < c17[KK-1]) {
                            #pragma unroll
                            for (int k = KK-1; k >= 1; --k) c17[k] = fminf(c17[k], fmaxf(c17[k-1], ee));
                            c17[0] = fminf(c17[0], ee);
                        }
                    }
                    const float th = c17[KK-1];
                    int kept = 0;
                    for (int n = 0; n < CAP; ++n) {
                        const unsigned short jj = s_bufJ[n][t];
                        const float ee = cand_e4(Pq[jj], xi, yi, zi);
                        if (ee <= th) { s_bufJ[kept][t] = jj; ++kept; }
                    }
                    cnt = kept;
                    tauL = fminf(tauL, th);
                }
            }
        }
    }

    // ---- Phase C: per-thread exact top-KK of survivors, merge -> exact tau ----
    {
        float c17[KK];
        #pragma unroll
        for (int k = 0; k < KK; ++k) c17[k] = 3.0e38f;
        for (int n = 0; n < cnt; ++n) {
            const float ee = cand_e4(Pq[s_bufJ[n][t]], xi, yi, zi);
            if (ee < c17[KK-1]) {
                #pragma unroll
                for (int k = KK-1; k >= 1; --k) c17[k] = fminf(c17[k], fmaxf(c17[k-1], ee));
                c17[0] = fminf(c17[0], ee);
            }
        }
        #pragma unroll
        for (int k = 0; k < KK; ++k) s_c17[k][t] = c17[k];
    }
    __syncthreads();
    if (t < 64) {
        const int mq = t & 31, half = t >> 5;
        float m[KK];
        #pragma unroll
        for (int k = 0; k < KK; ++k) m[k] = 3.0e38f;
        for (int s = 0; s < SPLITS/2; ++s) {
            const int r = mq + (half * (SPLITS/2) + s) * QPB;
            for (int k = 0; k < KK; ++k) {
                const float c = s_c17[k][r];
                if (c >= m[KK-1]) break;
                #pragma unroll
                for (int kk = KK-1; kk >= 1; --kk) m[kk] = fminf(m[kk], fmaxf(m[kk-1], c));
                m[0] = fminf(m[0], c);
            }
        }
        float tau = -3.0e38f;
        #pragma unroll
        for (int k = 0; k < KK; ++k) {
            const float bk = __shfl(m[KK-1-k], mq + 32, 64);
            tau = fmaxf(tau, fminf(m[k], bk));
        }
        if (half == 0) s_tau[mq] = tau;   // exact 17th (incl self) of all 8192
    }
    __syncthreads();
    const float tau = s_tau[lq];

    // ---- Phase D: accumulate |dist_ref - dist_pred| over accepted survivors ----
    const float4 selfp = Pp[i];
    float acc = 0.0f;
    for (int n = 0; n < cnt; ++n) {
        const int jj = s_bufJ[n][t];
        const float ee = cand_e4(Pq[jj], xi, yi, zi);
        if (ee <= tau) {
            const float d2r = fmaxf(ee + sqi, 0.0f);
            const float ep  = cand_e4(Pp[jj], selfp.x, selfp.y, selfp.z);
            const float d2p = fmaxf(ep + selfp.w, 0.0f);
            acc += fabsf(sqrtf(d2r) - sqrtf(d2p));
        }
    }

    #pragma unroll
    for (int off = 32; off > 0; off >>= 1) acc += __shfl_down(acc, off, 64);
    if ((t & 63) == 0) s_part[t >> 6] = acc;
    __syncthreads();
    if (t == 0) {
        float s = 0.0f;
        #pragma unroll
        for (int w = 0; w < BLOCK / 64; ++w) s += s_part[w];
        atomicAdd(acc_ws, s);
    }
}

extern "C" void kernel_launch(void* const* d_in, const int* in_sizes, int n_in,
                              void* d_out, int out_size, void* d_ws, size_t ws_size,
                              hipStream_t stream) {
    const float* pref = (const float*)d_in[0];
    const float* pts  = (const float*)d_in[1];
    float*  wsf = (float*)d_ws;
    float*  acc = wsf;                         // ws[0]: loss accumulator
    float4* P4r = (float4*)(wsf + 4);          // 512 KB
    float4* P4p = P4r + BATCH * NPTS;          // 512 KB
    float*  out = (float*)d_out;

    const int n = BATCH * NPTS;
    pel_pack<<<(n + 255) / 256, 256, 0, stream>>>(pref, pts, P4r, P4p, acc);
    pel_main<<<n / QPB, BLOCK, 0, stream>>>(P4r, P4p, acc);
    pel_finalize<<<1, 1, 0, stream>>>(acc, out);
}